// Round 1
// baseline (219.985 us; speedup 1.0000x reference)
//
#include <hip/hip_runtime.h>

// Problem constants
#define NB 16          // batch
#define NV 8           // vars per sample
#define HW 512         // H = W
#define PH 16          // patch h = w
#define GH 32          // grid h = w (512/16)
#define ED 128         // embed dim
#define KD 256         // 16*16 patch elems
#define MAXV 10

#define LDS_STRIDE 264 // 256 + 8 bf16 pad (16B) -> keeps ds_read_b128 16B-aligned, 2-way max aliasing

typedef __bf16 bf16x8 __attribute__((ext_vector_type(8)));
typedef __bf16 bf16x4 __attribute__((ext_vector_type(4)));
typedef float  f32x4  __attribute__((ext_vector_type(4)));

// ---------------------------------------------------------------------------
// Pack fp32 weights -> bf16 in B-fragment order:
//   packed[var*32768 + kb*4096 + n*32 + t]  where k = kb*32 + t, t = quad*8 + j
// A lane (l) of the main kernel reads bf16x8 at offset
//   var*32768 + kb*4096 + (n0 + (l&15))*32 + (l>>4)*8      (16B aligned)
// so a 64-lane wave covers 4096 contiguous bytes -> fully coalesced.
// ---------------------------------------------------------------------------
__global__ __launch_bounds__(256) void pack_weights(const float* __restrict__ w,
                                                    __bf16* __restrict__ packed) {
    int tid = blockIdx.x * 256 + threadIdx.x;
    if (tid >= MAXV * ED * KD) return;
    int t   = tid & 31;
    int n   = (tid >> 5) & 127;
    int kb  = (tid >> 12) & 7;
    int var = tid >> 15;
    int k   = kb * 32 + t;
    // src: proj_weights[var, n, 0, p, q] flat = (var*128 + n)*256 + k
    float f = w[(var * ED + n) * KD + k];
    packed[tid] = (__bf16)f;
}

// ---------------------------------------------------------------------------
// Main kernel: one block per (b, v, h-strip). 256 threads = 4 waves.
// Each wave computes a 32(patch) x 32(emb) tile via 16x16x32 bf16 MFMA.
// ---------------------------------------------------------------------------
__global__ __launch_bounds__(256) void patch_embed(
    const float* __restrict__ x,
    const int*   __restrict__ in_vars,
    const __bf16* __restrict__ wpacked,
    const float* __restrict__ bias,
    float* __restrict__ out)
{
    __shared__ __bf16 As[32 * LDS_STRIDE];   // A[m=patch 0..31][k=p*16+q], padded

    const int bx  = blockIdx.x;
    const int h   = bx & 31;
    const int v   = (bx >> 5) & 7;
    const int b   = bx >> 8;
    const int tid = threadIdx.x;

    const int var = in_vars[v];

    const float* xb = x + (((size_t)(b * NV + v)) * HW + (size_t)h * PH) * HW;

    // ---- stage 16x512 fp32 strip -> bf16 LDS (2048 float4 loads, coalesced) ----
    #pragma unroll
    for (int i = 0; i < 8; ++i) {
        int idx = tid + i * 256;        // 0..2047
        int p   = idx >> 7;             // row within strip 0..15
        int c   = (idx & 127) << 2;     // col 0..508 step 4
        float4 f = *(const float4*)(xb + (size_t)p * HW + c);
        int m = c >> 4;                 // patch (w) index
        int q = c & 15;                 // 0,4,8,12 -> stays inside one patch
        bf16x4 bv;
        bv.x = (__bf16)f.x; bv.y = (__bf16)f.y; bv.z = (__bf16)f.z; bv.w = (__bf16)f.w;
        *(bf16x4*)&As[m * LDS_STRIDE + p * PH + q] = bv;
    }
    __syncthreads();

    const int wave  = tid >> 6;
    const int lane  = tid & 63;
    const int lo    = lane & 15;
    const int quad  = lane >> 4;
    const int nwave = wave * 32;        // this wave's emb-column base

    const __bf16* wbase = wpacked + (size_t)var * (ED * KD);

    f32x4 acc[2][2];
    #pragma unroll
    for (int i = 0; i < 2; ++i)
        #pragma unroll
        for (int j = 0; j < 2; ++j)
            acc[i][j] = (f32x4){0.f, 0.f, 0.f, 0.f};

    #pragma unroll
    for (int kb = 0; kb < 8; ++kb) {
        bf16x8 aF[2], bF[2];
        #pragma unroll
        for (int i = 0; i < 2; ++i) {
            // A[m = i*16 + lo][k = kb*32 + quad*8 ..+7]
            aF[i] = *(const bf16x8*)&As[(i * 16 + lo) * LDS_STRIDE + kb * 32 + quad * 8];
        }
        #pragma unroll
        for (int j = 0; j < 2; ++j) {
            // B[k = kb*32 + quad*8 ..+7][n = nwave + j*16 + lo]
            bF[j] = *(const bf16x8*)&wbase[kb * 4096 + (nwave + j * 16 + lo) * 32 + quad * 8];
        }
        #pragma unroll
        for (int i = 0; i < 2; ++i)
            #pragma unroll
            for (int j = 0; j < 2; ++j)
                acc[i][j] = __builtin_amdgcn_mfma_f32_16x16x32_bf16(aF[i], bF[j], acc[i][j], 0, 0, 0);
    }

    // ---- epilogue: C/D layout col = lane&15, row = quad*4 + reg ----
    float bv[2];
    #pragma unroll
    for (int j = 0; j < 2; ++j)
        bv[j] = bias[var * ED + nwave + j * 16 + lo];

    const size_t outbase = ((size_t)(b * NV + v)) * (GH * GH) + (size_t)h * GH;
    #pragma unroll
    for (int i = 0; i < 2; ++i) {
        #pragma unroll
        for (int r = 0; r < 4; ++r) {
            int m = i * 16 + quad * 4 + r;   // patch w index
            #pragma unroll
            for (int j = 0; j < 2; ++j) {
                int e = nwave + j * 16 + lo;
                out[(outbase + m) * ED + e] = acc[i][j][r] + bv[j];
            }
        }
    }
}

extern "C" void kernel_launch(void* const* d_in, const int* in_sizes, int n_in,
                              void* d_out, int out_size, void* d_ws, size_t ws_size,
                              hipStream_t stream) {
    const float* x       = (const float*)d_in[0];
    const int*   in_vars = (const int*)d_in[1];
    const float* w       = (const float*)d_in[2];
    const float* bias    = (const float*)d_in[3];
    float*       out     = (float*)d_out;
    __bf16*      wpacked = (__bf16*)d_ws;   // 655,360 B needed

    hipLaunchKernelGGL(pack_weights, dim3((MAXV * ED * KD + 255) / 256), dim3(256), 0, stream,
                       w, wpacked);
    hipLaunchKernelGGL(patch_embed, dim3(NB * NV * GH), dim3(256), 0, stream,
                       x, in_vars, wpacked, bias, out);
}